// Round 1
// baseline (4534.546 us; speedup 1.0000x reference)
//
#include <hip/hip_runtime.h>

// Round 12: occupancy fix. rocprof r11: OccupancyPercent=11.5% (grid 256 =
// exactly 1 block/CU = 1 wave/SIMD), VALUBusy=47%, HBM 4% -> stall-bound,
// not mix-bound (295us x 0.47 = 139us of VALU work vs 109us FMA floor).
// Change: split-K x4 at the bit-exact flush boundaries. Required semantics =
// 4 serial 512-k chunks summed in order (((0+c0)+c1)+c2)+c3; that IS a 4-way
// split-K: each chunk block starts acc=0, runs serial k-ascending fp32 FMA,
// writes its chunk to a partial slab; reduce_k4 does the ordered __fadd_rn
// chain (+ optional Addm add) -> bit-identical to r11's flush+epilogue.
// Grid 16x16x4 = 1024 blocks = 4 blocks/CU = 4 waves/SIMD; dropping tot[8][8]
// frees 64 VGPRs so __launch_bounds__(256,4) fits (<=128 VGPR) without spill.
// Needs 12 slabs (192 MiB) of ws; falls back to the r11 path if ws is smaller.

#define NMAT 2048

constexpr int FM = 128, FN = 128, FK = 16; // 256 threads, 8x8 out/thread
constexpr int LDA = FM + 4;                // 132 floats: 16B-multiple rows
constexpr int LDB = FN + 4;
constexpr int KCHUNK = 512;                // flush granularity (bit-exact)

// ---------- split-K chunk kernel: acc over k in [z*512, (z+1)*512) ----------
__global__ __launch_bounds__(256, 4) void sgemm_chunk(
    const float* __restrict__ Am, const float* __restrict__ Bm,
    float* __restrict__ Pm) {
  __shared__ float As[FK][LDA]; // [k][m]
  __shared__ float Bs[FK][LDB]; // [k][n]
  const int tid = threadIdx.x;
  const int row0 = blockIdx.y * FM;
  const int col0 = blockIdx.x * FN;
  const int kb = blockIdx.z * KCHUNK;
  const int ty = tid >> 4; // 0..15 -> rows {ty*4..+3, 64+ty*4..+3}
  const int tx = tid & 15; // 0..15 -> cols {tx*4..+3, 64+tx*4..+3}

  // staging indices (two passes: idx = tid, tid+256)
  const int ar = tid >> 2;      // 0..63   (second pass: +64)
  const int ac = (tid & 3) * 4; // 0,4,8,12
  const int bk = tid >> 5;      // 0..7    (second pass: +8)
  const int bc = (tid & 31) * 4;

  float acc[8][8] = {};
  float4 va0, va1, vb0, vb1;

  const float* pa0 = &Am[(size_t)(row0 + ar) * NMAT + kb + ac];
  const float* pa1 = pa0 + (size_t)64 * NMAT;
  const float* pb0 = &Bm[(size_t)(kb + bk) * NMAT + col0 + bc];
  const float* pb1 = pb0 + (size_t)8 * NMAT;

  // preload first tile of this chunk into registers
  va0 = *(const float4*)pa0;
  va1 = *(const float4*)pa1;
  vb0 = *(const float4*)pb0;
  vb1 = *(const float4*)pb1;

#pragma unroll 1
  for (int t = 0; t < KCHUNK / FK; ++t) {
    __syncthreads(); // previous compute done -> safe to overwrite LDS
    As[ac + 0][ar] = va0.x;
    As[ac + 1][ar] = va0.y;
    As[ac + 2][ar] = va0.z;
    As[ac + 3][ar] = va0.w;
    As[ac + 0][ar + 64] = va1.x;
    As[ac + 1][ar + 64] = va1.y;
    As[ac + 2][ar + 64] = va1.z;
    As[ac + 3][ar + 64] = va1.w;
    *(float4*)&Bs[bk][bc] = vb0;
    *(float4*)&Bs[bk + 8][bc] = vb1;
    __syncthreads();

    // prefetch next tile into registers (lands during the FMA block)
    if (t + 1 < KCHUNK / FK) {
      pa0 += FK;
      pa1 += FK;
      pb0 += (size_t)FK * NMAT;
      pb1 += (size_t)FK * NMAT;
      va0 = *(const float4*)pa0;
      va1 = *(const float4*)pa1;
      vb0 = *(const float4*)pb0;
      vb1 = *(const float4*)pb1;
    }

    // compute: 16 k-steps, serial k-ascending per element (bit-exact order)
#pragma unroll
    for (int k = 0; k < FK; ++k) {
      const float4 a0 = *(const float4*)&As[k][ty * 4];
      const float4 a1 = *(const float4*)&As[k][64 + ty * 4];
      const float4 b0 = *(const float4*)&Bs[k][tx * 4];
      const float4 b1 = *(const float4*)&Bs[k][64 + tx * 4];
      const float af[8] = {a0.x, a0.y, a0.z, a0.w, a1.x, a1.y, a1.z, a1.w};
      const float bf[8] = {b0.x, b0.y, b0.z, b0.w, b1.x, b1.y, b1.z, b1.w};
#pragma unroll
      for (int i = 0; i < 8; ++i)
#pragma unroll
        for (int j = 0; j < 8; ++j)
          acc[i][j] = fmaf(af[i], bf[j], acc[i][j]);
    }
  }

  // write raw chunk accumulator to partial slab z (no flush/add here)
  float* dst = Pm + (size_t)blockIdx.z * NMAT * NMAT;
#pragma unroll
  for (int i = 0; i < 8; ++i) {
    const int r = row0 + ((i < 4) ? (ty * 4 + i) : (64 + ty * 4 + (i - 4)));
#pragma unroll
    for (int jb = 0; jb < 2; ++jb) {
      const int c = col0 + ((jb == 0) ? (tx * 4) : (64 + tx * 4));
      float4 v;
      v.x = acc[i][jb * 4 + 0];
      v.y = acc[i][jb * 4 + 1];
      v.z = acc[i][jb * 4 + 2];
      v.w = acc[i][jb * 4 + 3];
      *(float4*)&dst[(size_t)r * NMAT + c] = v;
    }
  }
}

// ordered reduction: out = (((0+c0)+c1)+c2)+c3 [+ Addm], one fp32 rounding per
// add — bit-identical to r11's tot-flush chain + epilogue add.
template <int DO_ADD>
__global__ __launch_bounds__(256) void reduce_k4(
    const float* __restrict__ Pm, const float* __restrict__ Addm,
    float* __restrict__ outp) {
  const size_t NN = (size_t)NMAT * NMAT;
  const size_t i = ((size_t)blockIdx.x * 256 + threadIdx.x) * 4;
  const float4 c0 = *(const float4*)&Pm[i];
  const float4 c1 = *(const float4*)&Pm[i + NN];
  const float4 c2 = *(const float4*)&Pm[i + 2 * NN];
  const float4 c3 = *(const float4*)&Pm[i + 3 * NN];
  float4 v;
  v.x = __fadd_rn(__fadd_rn(__fadd_rn(__fadd_rn(0.0f, c0.x), c1.x), c2.x), c3.x);
  v.y = __fadd_rn(__fadd_rn(__fadd_rn(__fadd_rn(0.0f, c0.y), c1.y), c2.y), c3.y);
  v.z = __fadd_rn(__fadd_rn(__fadd_rn(__fadd_rn(0.0f, c0.z), c1.z), c2.z), c3.z);
  v.w = __fadd_rn(__fadd_rn(__fadd_rn(__fadd_rn(0.0f, c0.w), c1.w), c2.w), c3.w);
  if (DO_ADD) {
    const float4 ad = *(const float4*)&Addm[i];
    v.x = __fadd_rn(v.x, ad.x);
    v.y = __fadd_rn(v.y, ad.y);
    v.z = __fadd_rn(v.z, ad.z);
    v.w = __fadd_rn(v.w, ad.w);
  }
  *(float4*)&outp[i] = v;
}

// ---------- fallback: r11 full-K kernel (used only if ws too small) ----------
template <int DO_ADD>
__global__ __launch_bounds__(256) void sgemm512(
    const float* __restrict__ Am, const float* __restrict__ Bm, float* Cm,
    const float* Addm) {
  __shared__ float As[FK][LDA];
  __shared__ float Bs[FK][LDB];
  const int tid = threadIdx.x;
  const int row0 = blockIdx.y * FM;
  const int col0 = blockIdx.x * FN;
  const int ty = tid >> 4;
  const int tx = tid & 15;
  const int ar = tid >> 2;
  const int ac = (tid & 3) * 4;
  const int bk = tid >> 5;
  const int bc = (tid & 31) * 4;

  float tot[8][8] = {};
  float acc[8][8] = {};
  float4 va0, va1, vb0, vb1;

  va0 = *(const float4*)&Am[(size_t)(row0 + ar) * NMAT + ac];
  va1 = *(const float4*)&Am[(size_t)(row0 + ar + 64) * NMAT + ac];
  vb0 = *(const float4*)&Bm[(size_t)bk * NMAT + col0 + bc];
  vb1 = *(const float4*)&Bm[(size_t)(bk + 8) * NMAT + col0 + bc];

  for (int k0 = 0; k0 < NMAT; k0 += FK) {
    __syncthreads();
    As[ac + 0][ar] = va0.x;
    As[ac + 1][ar] = va0.y;
    As[ac + 2][ar] = va0.z;
    As[ac + 3][ar] = va0.w;
    As[ac + 0][ar + 64] = va1.x;
    As[ac + 1][ar + 64] = va1.y;
    As[ac + 2][ar + 64] = va1.z;
    As[ac + 3][ar + 64] = va1.w;
    *(float4*)&Bs[bk][bc] = vb0;
    *(float4*)&Bs[bk + 8][bc] = vb1;
    __syncthreads();

    if (k0 + FK < NMAT) {
      const int kn = k0 + FK;
      va0 = *(const float4*)&Am[(size_t)(row0 + ar) * NMAT + kn + ac];
      va1 = *(const float4*)&Am[(size_t)(row0 + ar + 64) * NMAT + kn + ac];
      vb0 = *(const float4*)&Bm[(size_t)(kn + bk) * NMAT + col0 + bc];
      vb1 = *(const float4*)&Bm[(size_t)(kn + bk + 8) * NMAT + col0 + bc];
    }

#pragma unroll
    for (int k = 0; k < FK; ++k) {
      const float4 a0 = *(const float4*)&As[k][ty * 4];
      const float4 a1 = *(const float4*)&As[k][64 + ty * 4];
      const float4 b0 = *(const float4*)&Bs[k][tx * 4];
      const float4 b1 = *(const float4*)&Bs[k][64 + tx * 4];
      const float af[8] = {a0.x, a0.y, a0.z, a0.w, a1.x, a1.y, a1.z, a1.w};
      const float bf[8] = {b0.x, b0.y, b0.z, b0.w, b1.x, b1.y, b1.z, b1.w};
#pragma unroll
      for (int i = 0; i < 8; ++i)
#pragma unroll
        for (int j = 0; j < 8; ++j)
          acc[i][j] = fmaf(af[i], bf[j], acc[i][j]);
    }

    if (((k0 + FK) & 511) == 0) {
#pragma unroll
      for (int i = 0; i < 8; ++i)
#pragma unroll
        for (int j = 0; j < 8; ++j) {
          tot[i][j] = __fadd_rn(tot[i][j], acc[i][j]);
          acc[i][j] = 0.0f;
        }
    }
  }

#pragma unroll
  for (int i = 0; i < 8; ++i) {
    const int r = row0 + ((i < 4) ? (ty * 4 + i) : (64 + ty * 4 + (i - 4)));
#pragma unroll
    for (int jb = 0; jb < 2; ++jb) {
      const int c = col0 + ((jb == 0) ? (tx * 4) : (64 + tx * 4));
      const size_t idx = (size_t)r * NMAT + c;
      float4 v;
      v.x = tot[i][jb * 4 + 0];
      v.y = tot[i][jb * 4 + 1];
      v.z = tot[i][jb * 4 + 2];
      v.w = tot[i][jb * 4 + 3];
      if (DO_ADD) {
        const float4 ad = *(const float4*)&Addm[idx];
        v.x = __fadd_rn(v.x, ad.x);
        v.y = __fadd_rn(v.y, ad.y);
        v.z = __fadd_rn(v.z, ad.z);
        v.w = __fadd_rn(v.w, ad.w);
      }
      *(float4*)&Cm[idx] = v;
    }
  }
}

// out = t1 - (t2 + t3*t4/t5), each op one fp32 rounding, numpy eval order.
__global__ __launch_bounds__(256) void final_fp32(
    const float* __restrict__ t1, const float* __restrict__ t2,
    const float* t3, const float* __restrict__ t4,
    const float* __restrict__ t5, float* outp) {
  size_t i = (size_t)blockIdx.x * 256 + threadIdx.x;
  float num = __fmul_rn(t3[i], t4[i]);
  float q = __fdiv_rn(num, t5[i]);
  float s = __fadd_rn(t2[i], q);
  outp[i] = __fsub_rn(t1[i], s);
}

extern "C" void kernel_launch(void* const* d_in, const int* in_sizes, int n_in,
                              void* d_out, int out_size, void* d_ws,
                              size_t ws_size, hipStream_t stream) {
  const float* X1 = (const float*)d_in[0];
  const float* X2 = (const float*)d_in[1];
  float* out = (float*)d_out;

  const size_t NN = (size_t)NMAT * NMAT;
  const size_t M32 = NN * sizeof(float); // 16 MiB
  char* w = (char*)d_ws;
  float* fA  = (float*)(w + 0 * M32);
  float* fB  = (float*)(w + 1 * M32);
  float* fC  = (float*)(w + 2 * M32);
  float* fD  = (float*)(w + 3 * M32);
  float* fP  = (float*)(w + 4 * M32);
  float* fQ  = (float*)(w + 5 * M32);
  float* t2f = (float*)(w + 6 * M32);
  float* t4f = (float*)(w + 7 * M32);
  float* fT  = (float*)(w + 2 * M32); // reuse fC slab (dead after t3)
  float* t5f = (float*)(w + 3 * M32); // reuse fD slab (dead after t4)

  dim3 blk(256);
  dim3 ew((unsigned)(NN / 256));

  if (ws_size >= 12 * M32) {
    // split-K path: 12 slabs = 192 MiB (8 named + 4 partial chunks)
    float* Pk = (float*)(w + 8 * M32); // 4 x 16 MiB partials
    dim3 gsk(NMAT / FN, NMAT / FM, 4); // 16 x 16 x 4 = 1024 blocks
    dim3 gr((unsigned)(NN / (256 * 4)));

    auto gemm = [&](const float* A, const float* B, float* dst,
                    const float* add) {
      sgemm_chunk<<<gsk, blk, 0, stream>>>(A, B, Pk);
      if (add)
        reduce_k4<1><<<gr, blk, 0, stream>>>(Pk, add, dst);
      else
        reduce_k4<0><<<gr, blk, 0, stream>>>(Pk, nullptr, dst);
    };

    gemm(X1, X1, fA, nullptr);  // A  = X1@X1
    gemm(X1, X2, fB, nullptr);  // B  = X1@X2
    gemm(X2, fB, fC, nullptr);  // C  = X2@B
    gemm(X2, fA, fD, nullptr);  // D  = X2@A
    gemm(fC, fA, fP, nullptr);  // P  = C@A
    gemm(fD, fB, fQ, nullptr);  // Q  = D@B
    gemm(fB, fA, out, fC);      // t3 = B@A + C
    gemm(fD, X2, t4f, fP);      // t4 = D@X2 + P
    gemm(fA, X2, t2f, fB);      // t2 = A@X2 + B
    gemm(fP, fA, fT, nullptr);  // T  = P@A
    gemm(fQ, fA, t5f, fT);      // t5 = Q@A + T
    final_fp32<<<ew, blk, 0, stream>>>(fA, t2f, out, t4f, t5f, out);
  } else {
    // fallback: r11 path (128 MiB ws)
    dim3 grid(NMAT / FN, NMAT / FM);
    sgemm512<0><<<grid, blk, 0, stream>>>(X1, X1, fA, nullptr);
    sgemm512<0><<<grid, blk, 0, stream>>>(X1, X2, fB, nullptr);
    sgemm512<0><<<grid, blk, 0, stream>>>(X2, fB, fC, nullptr);
    sgemm512<0><<<grid, blk, 0, stream>>>(X2, fA, fD, nullptr);
    sgemm512<0><<<grid, blk, 0, stream>>>(fC, fA, fP, nullptr);
    sgemm512<0><<<grid, blk, 0, stream>>>(fD, fB, fQ, nullptr);
    sgemm512<1><<<grid, blk, 0, stream>>>(fB, fA, out, fC);
    sgemm512<1><<<grid, blk, 0, stream>>>(fD, X2, t4f, fP);
    sgemm512<1><<<grid, blk, 0, stream>>>(fA, X2, t2f, fB);
    sgemm512<0><<<grid, blk, 0, stream>>>(fP, fA, fT, nullptr);
    sgemm512<1><<<grid, blk, 0, stream>>>(fQ, fA, t5f, fT);
    final_fp32<<<ew, blk, 0, stream>>>(fA, t2f, out, t4f, t5f, out);
  }
}

// Round 2
// 2349.946 us; speedup vs baseline: 1.9296x; 1.9296x over previous
//
#include <hip/hip_runtime.h>

// Round 13: fix r12's spill regression. r12 rocprof: VGPR_Count=64 (!) with
// __launch_bounds__(256,4) -> acc[8][8] spilled to scratch -> WRITE_SIZE
// 16MB->1.23GB/dispatch, FETCH 82->572MB, VALUBusy 29%, chunk dur 457us
// (worse than r11's 295us full-K). Occupancy mechanism itself worked
// (11.5->42%). Change vs r12: drop the min-waves clause -> plain
// __launch_bounds__(256). r11's near-identical code allocated 152 VGPRs
// spill-free; at ~150 VGPRs we get 3 waves/SIMD = 3 blocks/CU, grid 1024 =
// ~768 resident + 256-block tail. Predicted: chunk ~130-180us, WRITE back
// to ~65MB, VALUBusy 65-80%, total ~2.0ms.
// Bit-exactness unchanged: per-element serial k-ascending fp32 FMA in 512-k
// chunks, ordered (((0+c0)+c1)+c2)+c3 reduce + one Addm add = r11's chain.

#define NMAT 2048

constexpr int FM = 128, FN = 128, FK = 16; // 256 threads, 8x8 out/thread
constexpr int LDA = FM + 4;                // 132 floats: 16B-multiple rows
constexpr int LDB = FN + 4;
constexpr int KCHUNK = 512;                // flush granularity (bit-exact)

// ---------- split-K chunk kernel: acc over k in [z*512, (z+1)*512) ----------
__global__ __launch_bounds__(256) void sgemm_chunk(
    const float* __restrict__ Am, const float* __restrict__ Bm,
    float* __restrict__ Pm) {
  __shared__ float As[FK][LDA]; // [k][m]
  __shared__ float Bs[FK][LDB]; // [k][n]
  const int tid = threadIdx.x;
  const int row0 = blockIdx.y * FM;
  const int col0 = blockIdx.x * FN;
  const int kb = blockIdx.z * KCHUNK;
  const int ty = tid >> 4; // 0..15 -> rows {ty*4..+3, 64+ty*4..+3}
  const int tx = tid & 15; // 0..15 -> cols {tx*4..+3, 64+tx*4..+3}

  // staging indices (two passes: idx = tid, tid+256)
  const int ar = tid >> 2;      // 0..63   (second pass: +64)
  const int ac = (tid & 3) * 4; // 0,4,8,12
  const int bk = tid >> 5;      // 0..7    (second pass: +8)
  const int bc = (tid & 31) * 4;

  float acc[8][8] = {};
  float4 va0, va1, vb0, vb1;

  const float* pa0 = &Am[(size_t)(row0 + ar) * NMAT + kb + ac];
  const float* pa1 = pa0 + (size_t)64 * NMAT;
  const float* pb0 = &Bm[(size_t)(kb + bk) * NMAT + col0 + bc];
  const float* pb1 = pb0 + (size_t)8 * NMAT;

  // preload first tile of this chunk into registers
  va0 = *(const float4*)pa0;
  va1 = *(const float4*)pa1;
  vb0 = *(const float4*)pb0;
  vb1 = *(const float4*)pb1;

#pragma unroll 1
  for (int t = 0; t < KCHUNK / FK; ++t) {
    __syncthreads(); // previous compute done -> safe to overwrite LDS
    As[ac + 0][ar] = va0.x;
    As[ac + 1][ar] = va0.y;
    As[ac + 2][ar] = va0.z;
    As[ac + 3][ar] = va0.w;
    As[ac + 0][ar + 64] = va1.x;
    As[ac + 1][ar + 64] = va1.y;
    As[ac + 2][ar + 64] = va1.z;
    As[ac + 3][ar + 64] = va1.w;
    *(float4*)&Bs[bk][bc] = vb0;
    *(float4*)&Bs[bk + 8][bc] = vb1;
    __syncthreads();

    // prefetch next tile into registers (lands during the FMA block)
    if (t + 1 < KCHUNK / FK) {
      pa0 += FK;
      pa1 += FK;
      pb0 += (size_t)FK * NMAT;
      pb1 += (size_t)FK * NMAT;
      va0 = *(const float4*)pa0;
      va1 = *(const float4*)pa1;
      vb0 = *(const float4*)pb0;
      vb1 = *(const float4*)pb1;
    }

    // compute: 16 k-steps, serial k-ascending per element (bit-exact order)
#pragma unroll
    for (int k = 0; k < FK; ++k) {
      const float4 a0 = *(const float4*)&As[k][ty * 4];
      const float4 a1 = *(const float4*)&As[k][64 + ty * 4];
      const float4 b0 = *(const float4*)&Bs[k][tx * 4];
      const float4 b1 = *(const float4*)&Bs[k][64 + tx * 4];
      const float af[8] = {a0.x, a0.y, a0.z, a0.w, a1.x, a1.y, a1.z, a1.w};
      const float bf[8] = {b0.x, b0.y, b0.z, b0.w, b1.x, b1.y, b1.z, b1.w};
#pragma unroll
      for (int i = 0; i < 8; ++i)
#pragma unroll
        for (int j = 0; j < 8; ++j)
          acc[i][j] = fmaf(af[i], bf[j], acc[i][j]);
    }
  }

  // write raw chunk accumulator to partial slab z (no flush/add here)
  float* dst = Pm + (size_t)blockIdx.z * NMAT * NMAT;
#pragma unroll
  for (int i = 0; i < 8; ++i) {
    const int r = row0 + ((i < 4) ? (ty * 4 + i) : (64 + ty * 4 + (i - 4)));
#pragma unroll
    for (int jb = 0; jb < 2; ++jb) {
      const int c = col0 + ((jb == 0) ? (tx * 4) : (64 + tx * 4));
      float4 v;
      v.x = acc[i][jb * 4 + 0];
      v.y = acc[i][jb * 4 + 1];
      v.z = acc[i][jb * 4 + 2];
      v.w = acc[i][jb * 4 + 3];
      *(float4*)&dst[(size_t)r * NMAT + c] = v;
    }
  }
}

// ordered reduction: out = (((0+c0)+c1)+c2)+c3 [+ Addm], one fp32 rounding per
// add — bit-identical to r11's tot-flush chain + epilogue add.
template <int DO_ADD>
__global__ __launch_bounds__(256) void reduce_k4(
    const float* __restrict__ Pm, const float* __restrict__ Addm,
    float* __restrict__ outp) {
  const size_t NN = (size_t)NMAT * NMAT;
  const size_t i = ((size_t)blockIdx.x * 256 + threadIdx.x) * 4;
  const float4 c0 = *(const float4*)&Pm[i];
  const float4 c1 = *(const float4*)&Pm[i + NN];
  const float4 c2 = *(const float4*)&Pm[i + 2 * NN];
  const float4 c3 = *(const float4*)&Pm[i + 3 * NN];
  float4 v;
  v.x = __fadd_rn(__fadd_rn(__fadd_rn(__fadd_rn(0.0f, c0.x), c1.x), c2.x), c3.x);
  v.y = __fadd_rn(__fadd_rn(__fadd_rn(__fadd_rn(0.0f, c0.y), c1.y), c2.y), c3.y);
  v.z = __fadd_rn(__fadd_rn(__fadd_rn(__fadd_rn(0.0f, c0.z), c1.z), c2.z), c3.z);
  v.w = __fadd_rn(__fadd_rn(__fadd_rn(__fadd_rn(0.0f, c0.w), c1.w), c2.w), c3.w);
  if (DO_ADD) {
    const float4 ad = *(const float4*)&Addm[i];
    v.x = __fadd_rn(v.x, ad.x);
    v.y = __fadd_rn(v.y, ad.y);
    v.z = __fadd_rn(v.z, ad.z);
    v.w = __fadd_rn(v.w, ad.w);
  }
  *(float4*)&outp[i] = v;
}

// ---------- fallback: r11 full-K kernel (used only if ws too small) ----------
template <int DO_ADD>
__global__ __launch_bounds__(256) void sgemm512(
    const float* __restrict__ Am, const float* __restrict__ Bm, float* Cm,
    const float* Addm) {
  __shared__ float As[FK][LDA];
  __shared__ float Bs[FK][LDB];
  const int tid = threadIdx.x;
  const int row0 = blockIdx.y * FM;
  const int col0 = blockIdx.x * FN;
  const int ty = tid >> 4;
  const int tx = tid & 15;
  const int ar = tid >> 2;
  const int ac = (tid & 3) * 4;
  const int bk = tid >> 5;
  const int bc = (tid & 31) * 4;

  float tot[8][8] = {};
  float acc[8][8] = {};
  float4 va0, va1, vb0, vb1;

  va0 = *(const float4*)&Am[(size_t)(row0 + ar) * NMAT + ac];
  va1 = *(const float4*)&Am[(size_t)(row0 + ar + 64) * NMAT + ac];
  vb0 = *(const float4*)&Bm[(size_t)bk * NMAT + col0 + bc];
  vb1 = *(const float4*)&Bm[(size_t)(bk + 8) * NMAT + col0 + bc];

  for (int k0 = 0; k0 < NMAT; k0 += FK) {
    __syncthreads();
    As[ac + 0][ar] = va0.x;
    As[ac + 1][ar] = va0.y;
    As[ac + 2][ar] = va0.z;
    As[ac + 3][ar] = va0.w;
    As[ac + 0][ar + 64] = va1.x;
    As[ac + 1][ar + 64] = va1.y;
    As[ac + 2][ar + 64] = va1.z;
    As[ac + 3][ar + 64] = va1.w;
    *(float4*)&Bs[bk][bc] = vb0;
    *(float4*)&Bs[bk + 8][bc] = vb1;
    __syncthreads();

    if (k0 + FK < NMAT) {
      const int kn = k0 + FK;
      va0 = *(const float4*)&Am[(size_t)(row0 + ar) * NMAT + kn + ac];
      va1 = *(const float4*)&Am[(size_t)(row0 + ar + 64) * NMAT + kn + ac];
      vb0 = *(const float4*)&Bm[(size_t)(kn + bk) * NMAT + col0 + bc];
      vb1 = *(const float4*)&Bm[(size_t)(kn + bk + 8) * NMAT + col0 + bc];
    }

#pragma unroll
    for (int k = 0; k < FK; ++k) {
      const float4 a0 = *(const float4*)&As[k][ty * 4];
      const float4 a1 = *(const float4*)&As[k][64 + ty * 4];
      const float4 b0 = *(const float4*)&Bs[k][tx * 4];
      const float4 b1 = *(const float4*)&Bs[k][64 + tx * 4];
      const float af[8] = {a0.x, a0.y, a0.z, a0.w, a1.x, a1.y, a1.z, a1.w};
      const float bf[8] = {b0.x, b0.y, b0.z, b0.w, b1.x, b1.y, b1.z, b1.w};
#pragma unroll
      for (int i = 0; i < 8; ++i)
#pragma unroll
        for (int j = 0; j < 8; ++j)
          acc[i][j] = fmaf(af[i], bf[j], acc[i][j]);
    }

    if (((k0 + FK) & 511) == 0) {
#pragma unroll
      for (int i = 0; i < 8; ++i)
#pragma unroll
        for (int j = 0; j < 8; ++j) {
          tot[i][j] = __fadd_rn(tot[i][j], acc[i][j]);
          acc[i][j] = 0.0f;
        }
    }
  }

#pragma unroll
  for (int i = 0; i < 8; ++i) {
    const int r = row0 + ((i < 4) ? (ty * 4 + i) : (64 + ty * 4 + (i - 4)));
#pragma unroll
    for (int jb = 0; jb < 2; ++jb) {
      const int c = col0 + ((jb == 0) ? (tx * 4) : (64 + tx * 4));
      const size_t idx = (size_t)r * NMAT + c;
      float4 v;
      v.x = tot[i][jb * 4 + 0];
      v.y = tot[i][jb * 4 + 1];
      v.z = tot[i][jb * 4 + 2];
      v.w = tot[i][jb * 4 + 3];
      if (DO_ADD) {
        const float4 ad = *(const float4*)&Addm[idx];
        v.x = __fadd_rn(v.x, ad.x);
        v.y = __fadd_rn(v.y, ad.y);
        v.z = __fadd_rn(v.z, ad.z);
        v.w = __fadd_rn(v.w, ad.w);
      }
      *(float4*)&Cm[idx] = v;
    }
  }
}

// out = t1 - (t2 + t3*t4/t5), each op one fp32 rounding, numpy eval order.
__global__ __launch_bounds__(256) void final_fp32(
    const float* __restrict__ t1, const float* __restrict__ t2,
    const float* t3, const float* __restrict__ t4,
    const float* __restrict__ t5, float* outp) {
  size_t i = (size_t)blockIdx.x * 256 + threadIdx.x;
  float num = __fmul_rn(t3[i], t4[i]);
  float q = __fdiv_rn(num, t5[i]);
  float s = __fadd_rn(t2[i], q);
  outp[i] = __fsub_rn(t1[i], s);
}

extern "C" void kernel_launch(void* const* d_in, const int* in_sizes, int n_in,
                              void* d_out, int out_size, void* d_ws,
                              size_t ws_size, hipStream_t stream) {
  const float* X1 = (const float*)d_in[0];
  const float* X2 = (const float*)d_in[1];
  float* out = (float*)d_out;

  const size_t NN = (size_t)NMAT * NMAT;
  const size_t M32 = NN * sizeof(float); // 16 MiB
  char* w = (char*)d_ws;
  float* fA  = (float*)(w + 0 * M32);
  float* fB  = (float*)(w + 1 * M32);
  float* fC  = (float*)(w + 2 * M32);
  float* fD  = (float*)(w + 3 * M32);
  float* fP  = (float*)(w + 4 * M32);
  float* fQ  = (float*)(w + 5 * M32);
  float* t2f = (float*)(w + 6 * M32);
  float* t4f = (float*)(w + 7 * M32);
  float* fT  = (float*)(w + 2 * M32); // reuse fC slab (dead after t3)
  float* t5f = (float*)(w + 3 * M32); // reuse fD slab (dead after t4)

  dim3 blk(256);
  dim3 ew((unsigned)(NN / 256));

  if (ws_size >= 12 * M32) {
    // split-K path: 12 slabs = 192 MiB (8 named + 4 partial chunks)
    float* Pk = (float*)(w + 8 * M32); // 4 x 16 MiB partials
    dim3 gsk(NMAT / FN, NMAT / FM, 4); // 16 x 16 x 4 = 1024 blocks
    dim3 gr((unsigned)(NN / (256 * 4)));

    auto gemm = [&](const float* A, const float* B, float* dst,
                    const float* add) {
      sgemm_chunk<<<gsk, blk, 0, stream>>>(A, B, Pk);
      if (add)
        reduce_k4<1><<<gr, blk, 0, stream>>>(Pk, add, dst);
      else
        reduce_k4<0><<<gr, blk, 0, stream>>>(Pk, nullptr, dst);
    };

    gemm(X1, X1, fA, nullptr);  // A  = X1@X1
    gemm(X1, X2, fB, nullptr);  // B  = X1@X2
    gemm(X2, fB, fC, nullptr);  // C  = X2@B
    gemm(X2, fA, fD, nullptr);  // D  = X2@A
    gemm(fC, fA, fP, nullptr);  // P  = C@A
    gemm(fD, fB, fQ, nullptr);  // Q  = D@B
    gemm(fB, fA, out, fC);      // t3 = B@A + C
    gemm(fD, X2, t4f, fP);      // t4 = D@X2 + P
    gemm(fA, X2, t2f, fB);      // t2 = A@X2 + B
    gemm(fP, fA, fT, nullptr);  // T  = P@A
    gemm(fQ, fA, t5f, fT);      // t5 = Q@A + T
    final_fp32<<<ew, blk, 0, stream>>>(fA, t2f, out, t4f, t5f, out);
  } else {
    // fallback: r11 path (128 MiB ws)
    dim3 grid(NMAT / FN, NMAT / FM);
    sgemm512<0><<<grid, blk, 0, stream>>>(X1, X1, fA, nullptr);
    sgemm512<0><<<grid, blk, 0, stream>>>(X1, X2, fB, nullptr);
    sgemm512<0><<<grid, blk, 0, stream>>>(X2, fB, fC, nullptr);
    sgemm512<0><<<grid, blk, 0, stream>>>(X2, fA, fD, nullptr);
    sgemm512<0><<<grid, blk, 0, stream>>>(fC, fA, fP, nullptr);
    sgemm512<0><<<grid, blk, 0, stream>>>(fD, fB, fQ, nullptr);
    sgemm512<1><<<grid, blk, 0, stream>>>(fB, fA, out, fC);
    sgemm512<1><<<grid, blk, 0, stream>>>(fD, X2, t4f, fP);
    sgemm512<1><<<grid, blk, 0, stream>>>(fA, X2, t2f, fB);
    sgemm512<0><<<grid, blk, 0, stream>>>(fP, fA, fT, nullptr);
    sgemm512<1><<<grid, blk, 0, stream>>>(fQ, fA, t5f, fT);
    final_fp32<<<ew, blk, 0, stream>>>(fA, t2f, out, t4f, t5f, out);
  }
}